// Round 1
// baseline (114.285 us; speedup 1.0000x reference)
//
#include <hip/hip_runtime.h>

// SKA 2D: out[b, g*8+cw, h, w] = sum_{i,j} x[b, g*8+cw, h+i-1, w+j-1] * w[b, cw, 3i+j, h, w]
// B=8, C=64, H=W=128, C_w=8, ks=3, groups=8. fp32 in/out. Memory-bound (~105 MB).

#define SKA_H 128
#define SKA_W 128
#define SKA_HW (SKA_H * SKA_W)

__global__ __launch_bounds__(256) void SKA_44830868635847_kernel(
        const float* __restrict__ x,
        const float* __restrict__ wgt,
        float* __restrict__ out) {
    // tid -> (b, cw, h, w4); w4 fastest so waves are coalesced along w,
    // and a 256-thread block covers 8 consecutive h rows (L1 catches the
    // 3-row vertical halo reuse).
    int tid = blockIdx.x * 256 + threadIdx.x;
    int w4 = tid & 31;           // 32 chunks of 4 along W
    int h  = (tid >> 5) & 127;
    int cw = (tid >> 12) & 7;
    int b  = tid >> 15;
    int w0 = w4 * 4;

    // Load the 9 weight float4s once; reused across all 8 groups.
    const float* wbase = wgt + ((size_t)(b * 8 + cw) * 9) * SKA_HW + h * SKA_W + w0;
    float4 wv[9];
#pragma unroll
    for (int k = 0; k < 9; ++k)
        wv[k] = *(const float4*)(wbase + (size_t)k * SKA_HW);

    const bool has_left  = (w0 != 0);
    const bool has_right = (w0 != SKA_W - 4);

#pragma unroll
    for (int g = 0; g < 8; ++g) {
        int c = g * 8 + cw;
        const float* xc = x + (size_t)(b * 64 + c) * SKA_HW;
        float4 acc = make_float4(0.f, 0.f, 0.f, 0.f);
#pragma unroll
        for (int i = 0; i < 3; ++i) {
            int hr = h + i - 1;
            if (hr < 0 || hr >= SKA_H) continue;   // zero padding rows
            const float* xr = xc + hr * SKA_W + w0;
            float4 mid = *(const float4*)xr;       // cols w0..w0+3 (16B aligned)
            float xl = has_left  ? xr[-1] : 0.f;   // col w0-1
            float xr4 = has_right ? xr[4]  : 0.f;  // col w0+4
            float4 wl = wv[i * 3 + 0];
            float4 wm = wv[i * 3 + 1];
            float4 wr = wv[i * 3 + 2];
            // kernel col j=0 (offset -1): cols (w0-1 .. w0+2)
            acc.x += wl.x * xl;
            acc.y += wl.y * mid.x;
            acc.z += wl.z * mid.y;
            acc.w += wl.w * mid.z;
            // j=1 (offset 0): cols (w0 .. w0+3)
            acc.x += wm.x * mid.x;
            acc.y += wm.y * mid.y;
            acc.z += wm.z * mid.z;
            acc.w += wm.w * mid.w;
            // j=2 (offset +1): cols (w0+1 .. w0+4)
            acc.x += wr.x * mid.y;
            acc.y += wr.y * mid.z;
            acc.z += wr.z * mid.w;
            acc.w += wr.w * xr4;
        }
        *(float4*)(out + (size_t)(b * 64 + c) * SKA_HW + h * SKA_W + w0) = acc;
    }
}

extern "C" void kernel_launch(void* const* d_in, const int* in_sizes, int n_in,
                              void* d_out, int out_size, void* d_ws, size_t ws_size,
                              hipStream_t stream) {
    const float* x   = (const float*)d_in[0];  // (8, 64, 128, 128)
    const float* wgt = (const float*)d_in[1];  // (8, 8, 9, 128, 128)
    float* out = (float*)d_out;                // (8, 64, 128, 128)

    // threads = B * C_w * H * (W/4) = 8*8*128*32 = 262144
    const int total = 8 * 8 * 128 * 32;
    SKA_44830868635847_kernel<<<total / 256, 256, 0, stream>>>(x, wgt, out);
}

// Round 2
// 106.856 us; speedup vs baseline: 1.0695x; 1.0695x over previous
//
#include <hip/hip_runtime.h>

// SKA 2D: out[b, g*8+cw, h, w] = sum_{i,j} x[b, g*8+cw, h+i-1, w+j-1] * w[b, cw, 3i+j, h, w]
// B=8, C=64, H=W=128, C_w=8, ks=3, groups=8. fp32. Memory-bound, ideal ~105 MB HBM.
//
// Strategy: block = (b, cw, 8-row tile). Stage x for all 8 groups (8 channels x
// 10 rows x 128 cols = 40 KB) into LDS with coalesced float4 loads; weights in
// 9 float4 registers per thread (shared across groups -> exact 1x w traffic);
// horizontal halos via wave shuffles (zero scalar loads, zero bank conflicts).

#define SKA_W 128
#define SKA_HW (128 * 128)
#define TILE_ROWS 8
#define STAGE_ROWS 10  // tile rows + 1 halo row top/bottom

__global__ __launch_bounds__(256, 4) void SKA_44830868635847_kernel(
        const float* __restrict__ x,
        const float* __restrict__ wgt,
        float* __restrict__ out) {
    __shared__ float lds[8 * STAGE_ROWS * SKA_W];  // 40 KiB -> 4 blocks/CU

    const int t     = threadIdx.x;
    const int bid   = blockIdx.x;
    const int htile = bid & 15;          // 16 row-tiles of 8
    const int cw    = (bid >> 4) & 7;
    const int b     = bid >> 7;
    const int h0    = htile * TILE_ROWS;

    // ---- weights: 9 float4 per thread, loaded once, reused across all 8 groups
    const int w4 = t & 31;       // 32 float4-chunks across W
    const int hl = t >> 5;       // 8 rows per block
    const int h  = h0 + hl;
    const int w0 = w4 * 4;
    const float* wbase = wgt + ((size_t)(b * 8 + cw) * 9) * SKA_HW + h * SKA_W + w0;
    float4 wv[9];
#pragma unroll
    for (int k = 0; k < 9; ++k)
        wv[k] = *(const float4*)(wbase + (size_t)k * SKA_HW);

    // ---- stage x: 8 channels (g=0..7) x 10 rows x 128 cols, coalesced float4
    // 2560 float4 chunks / 256 threads = 10 per thread.
    const float* xb = x + (size_t)(b * 64 + cw) * SKA_HW;
#pragma unroll
    for (int rep = 0; rep < 10; ++rep) {
        int idx = rep * 256 + t;
        int ch  = idx / 320;             // 320 chunks per channel (10 rows x 32)
        int rem = idx - ch * 320;
        int r   = rem >> 5;
        int c4  = rem & 31;
        int xrow = h0 - 1 + r;
        float4 v = make_float4(0.f, 0.f, 0.f, 0.f);
        if ((unsigned)xrow < 128u)       // zero-pad rows outside the image
            v = *(const float4*)(xb + (size_t)ch * 8 * SKA_HW + xrow * SKA_W + c4 * 4);
        *(float4*)&lds[(ch * STAGE_ROWS + r) * SKA_W + c4 * 4] = v;
    }
    __syncthreads();

    // ---- compute: per group, 3 row taps from LDS; horizontal halos via shuffle
    const size_t obase = (size_t)(b * 64 + cw) * SKA_HW + (size_t)h * SKA_W + w0;
#pragma unroll
    for (int g = 0; g < 8; ++g) {
        float4 acc = make_float4(0.f, 0.f, 0.f, 0.f);
#pragma unroll
        for (int i = 0; i < 3; ++i) {
            const float* lrow = &lds[(g * STAGE_ROWS + hl + i) * SKA_W + w0];
            float4 mid = *(const float4*)lrow;
            // left/right halo from the lane-adjacent chunk (same row: w4 +-1).
            // Lanes 0/32 have w4==0 and lanes 31/63 have w4==31, so the
            // cross-row shuffle at the lane-31/32 boundary is always masked.
            float xl  = __shfl_up(mid.w, 1);
            xl  = (w4 == 0)  ? 0.f : xl;
            float xr4 = __shfl_down(mid.x, 1);
            xr4 = (w4 == 31) ? 0.f : xr4;
            float4 wl = wv[i * 3 + 0];
            float4 wm = wv[i * 3 + 1];
            float4 wr = wv[i * 3 + 2];
            acc.x += wl.x * xl    + wm.x * mid.x + wr.x * mid.y;
            acc.y += wl.y * mid.x + wm.y * mid.y + wr.y * mid.z;
            acc.z += wl.z * mid.y + wm.z * mid.z + wr.z * mid.w;
            acc.w += wl.w * mid.z + wm.w * mid.w + wr.w * xr4;
        }
        *(float4*)(out + obase + (size_t)g * 8 * SKA_HW) = acc;
    }
}

extern "C" void kernel_launch(void* const* d_in, const int* in_sizes, int n_in,
                              void* d_out, int out_size, void* d_ws, size_t ws_size,
                              hipStream_t stream) {
    const float* x   = (const float*)d_in[0];  // (8, 64, 128, 128)
    const float* wgt = (const float*)d_in[1];  // (8, 8, 9, 128, 128)
    float* out = (float*)d_out;                // (8, 64, 128, 128)

    // blocks = B * C_w * (H / TILE_ROWS) = 8*8*16 = 1024
    SKA_44830868635847_kernel<<<1024, 256, 0, stream>>>(x, wgt, out);
}